// Round 2
// baseline (426.681 us; speedup 1.0000x reference)
//
#include <hip/hip_runtime.h>
#include <hip/hip_fp16.h>

// 3-layer gather-GEMM GNN (N=262144, K=8, 16->128->128->16), f16 MFMA.
// Scaled messages prescaled by 2^-8 (folded into inv_dist) to avoid fp16
// overflow; epilogue multiplies accumulator by 256 before bias.
//
// Workspace budget: ws holds ONLY h1+h2 (64 MiB each = 128 MiB exactly).
// invd/h16/shuffled-W live in d_out (16 MiB scratch until layer 2 overwrites
// it); layer 2's invd+Wf2 are d2d-copied into the dead h1 region first so
// layer 2 never reads d_out while writing it.

typedef _Float16 f16x8 __attribute__((ext_vector_type(8)));
typedef float f32x4 __attribute__((ext_vector_type(4)));

#define NNODES 262144

__global__ __launch_bounds__(256) void conv_h_kernel(const float* __restrict__ h,
                                                     __half* __restrict__ h16, int n) {
    int i = blockIdx.x * 256 + threadIdx.x;
    if (i < n) h16[i] = __float2half(h[i]);
}

__global__ __launch_bounds__(256) void prep_edges_kernel(const float* __restrict__ pos,
                                                         const int* __restrict__ nbr,
                                                         __half* __restrict__ invd, int n_edges) {
    int e = blockIdx.x * 256 + threadIdx.x;
    if (e >= n_edges) return;
    int i = e >> 3;
    int n = nbr[e];
    float dx = pos[i * 3 + 0] - pos[n * 3 + 0];
    float dy = pos[i * 3 + 1] - pos[n * 3 + 1];
    float dz = pos[i * 3 + 2] - pos[n * 3 + 2];
    float d = sqrtf(dx * dx + dy * dy + dz * dz);
    if (d == 0.0f) d = 0.5f;                       // reference: where(dist==0, 0.5, dist)
    invd[e] = __float2half((1.0f / d) * 0.00390625f);  // prescale 1/256
}

// Pre-shuffle W [KT][FO] (row-major f32) into MFMA B-fragment order:
// Wf[((s*NT + t)*64 + lane)*8 + j] = W[s*32 + (lane>>4)*8 + j][t*16 + (lane&15)]
__global__ __launch_bounds__(256) void shuffle_w_kernel(const float* __restrict__ W,
                                                        __half* __restrict__ Wf,
                                                        int KT, int FO) {
    int e = blockIdx.x * 256 + threadIdx.x;
    if (e >= KT * FO) return;
    int j = e & 7;
    int lane = (e >> 3) & 63;
    int rest = e >> 9;
    int NT = FO >> 4;
    int t = rest % NT;
    int s = rest / NT;
    int k = s * 32 + (lane >> 4) * 8 + j;
    int n = t * 16 + (lane & 15);
    Wf[e] = __float2half(W[k * FO + n]);
}

// Fused gather + scale + GEMM layer.
// F_IN in {16,128}; stage = 128 K-columns (1 neighbor for F_IN=128, all 8 for F_IN=16).
template <int F_IN, int F_OUT, bool LEAKY, bool OUT_F32>
__global__ __launch_bounds__(256) void layer_kernel(
    const __half* __restrict__ hprev, const __half* __restrict__ invd,
    const int* __restrict__ nbr, const __half* __restrict__ Wf,
    const float* __restrict__ bias, void* __restrict__ outp) {
    constexpr int NT = F_OUT / 16;
    constexpr int NSTAGES = (8 * F_IN) / 128;
    constexpr int NBUF = (NSTAGES > 1) ? 2 : 1;
    constexpr int LDA = 136;  // 128 + 8 halves pad: conflict-free b128 reads

    __shared__ __align__(16) __half As[NBUF][64][LDA];

    const int tid = threadIdx.x;
    const int m0 = blockIdx.x * 64;
    const int wave = tid >> 6;
    const int lane = tid & 63;
    const int quad = lane >> 4;
    const int lmod = lane & 15;

    f32x4 acc[NT];
#pragma unroll
    for (int t = 0; t < NT; ++t) acc[t] = f32x4{0.f, 0.f, 0.f, 0.f};

    const int r = tid >> 2;   // staging row 0..63
    const int seg = tid & 3;  // 64B segment within 256B row (F_IN=128)
    const int i_node = m0 + r;

    auto stage = [&](int buf, int st) {
        if (F_IN == 128) {
            const int nb = st;
            const int n = nbr[i_node * 8 + nb];
            const __half inv = invd[i_node * 8 + nb];
            const __half2 s2 = __halves2half2(inv, inv);
            const uint4* src = (const uint4*)(hprev + (size_t)n * 128 + seg * 32);
            uint4* dst = (uint4*)(&As[buf][r][seg * 32]);
#pragma unroll
            for (int q = 0; q < 4; ++q) {
                uint4 x = src[q];
                __half2* xh = (__half2*)&x;
                xh[0] = __hmul2(xh[0], s2);
                xh[1] = __hmul2(xh[1], s2);
                xh[2] = __hmul2(xh[2], s2);
                xh[3] = __hmul2(xh[3], s2);
                dst[q] = x;
            }
        } else {
#pragma unroll
            for (int u = 0; u < 2; ++u) {
                const int nb = seg * 2 + u;
                const int n = nbr[i_node * 8 + nb];
                const __half inv = invd[i_node * 8 + nb];
                const __half2 s2 = __halves2half2(inv, inv);
                const uint4* src = (const uint4*)(hprev + (size_t)n * 16);
                uint4* dst = (uint4*)(&As[buf][r][nb * 16]);
#pragma unroll
                for (int q = 0; q < 2; ++q) {
                    uint4 x = src[q];
                    __half2* xh = (__half2*)&x;
                    xh[0] = __hmul2(xh[0], s2);
                    xh[1] = __hmul2(xh[1], s2);
                    xh[2] = __hmul2(xh[2], s2);
                    xh[3] = __hmul2(xh[3], s2);
                    dst[q] = x;
                }
            }
        }
    };

    stage(0, 0);
    for (int st = 0; st < NSTAGES; ++st) {
        __syncthreads();
        if (st + 1 < NSTAGES) stage((st + 1) & 1, st + 1);
        const int buf = st & (NBUF - 1);
        const __half* arow = &As[buf][wave * 16 + lmod][quad * 8];
#pragma unroll
        for (int ks = 0; ks < 4; ++ks) {
            f16x8 a = *(const f16x8*)(arow + ks * 32);
            const int s = st * 4 + ks;
#pragma unroll
            for (int t = 0; t < NT; ++t) {
                f16x8 b = *(const f16x8*)(Wf + (size_t)(((s * NT) + t) * 64 + lane) * 8);
                acc[t] = __builtin_amdgcn_mfma_f32_16x16x32_f16(a, b, acc[t], 0, 0, 0);
            }
        }
    }

    // Epilogue: D[row=quad*4+rr][col=lane&15] per 16x16 tile.
#pragma unroll
    for (int t = 0; t < NT; ++t) {
        const int col = t * 16 + lmod;
        const float bv = bias[col];
#pragma unroll
        for (int rr = 0; rr < 4; ++rr) {
            const int grow = m0 + wave * 16 + quad * 4 + rr;
            float v = acc[t][rr] * 256.0f + bv;
            if (LEAKY) v = (v >= 0.f) ? v : 0.01f * v;
            if (OUT_F32)
                ((float*)outp)[(size_t)grow * F_OUT + col] = v;
            else
                ((__half*)outp)[(size_t)grow * F_OUT + col] = __float2half(v);
        }
    }
}

extern "C" void kernel_launch(void* const* d_in, const int* in_sizes, int n_in,
                              void* d_out, int out_size, void* d_ws, size_t ws_size,
                              hipStream_t stream) {
    const float* h   = (const float*)d_in[0];
    const float* pos = (const float*)d_in[1];
    const int*   nbr = (const int*)d_in[2];
    const float* W0  = (const float*)d_in[3];
    const float* b0  = (const float*)d_in[4];
    const float* W1  = (const float*)d_in[5];
    const float* b1  = (const float*)d_in[6];
    const float* W2  = (const float*)d_in[7];
    const float* b2  = (const float*)d_in[8];

    const int N = NNODES;

    // ws: ONLY the two 64 MiB fp16 intermediates (128 MiB total).
    char* w = (char*)d_ws;
    __half* h1 = (__half*)w;                               // 67,108,864 B
    __half* h2 = (__half*)(w + (size_t)67108864);          // 67,108,864 B
    // layer-2 copies of invd/Wf2, placed in the dead h1 region:
    __half* invd2 = (__half*)w;                            // 4,194,304 B
    __half* W2f2  = (__half*)(w + (size_t)4194304);        // 32,768 B

    // d_out doubles as scratch until layer 2 overwrites all of it (16 MiB).
    char* ob = (char*)d_out;
    __half* invd = (__half*)(ob + 0);                      // 4,194,304 B
    __half* h16  = (__half*)(ob + 4194304);                // 8,388,608 B
    __half* W0f  = (__half*)(ob + 12582912);               // 32,768 B
    __half* W1f  = (__half*)(ob + 12615680);               // 262,144 B
    __half* W2f  = (__half*)(ob + 12877824);               // 32,768 B  (end 12,910,592 <= 16,777,216)

    conv_h_kernel<<<(N * 16 + 255) / 256, 256, 0, stream>>>(h, h16, N * 16);
    prep_edges_kernel<<<(N * 8 + 255) / 256, 256, 0, stream>>>(pos, nbr, invd, N * 8);
    shuffle_w_kernel<<<(128 * 128 + 255) / 256, 256, 0, stream>>>(W0, W0f, 128, 128);
    shuffle_w_kernel<<<(1024 * 128 + 255) / 256, 256, 0, stream>>>(W1, W1f, 1024, 128);
    shuffle_w_kernel<<<(1024 * 16 + 255) / 256, 256, 0, stream>>>(W2, W2f, 1024, 16);

    layer_kernel<16, 128, false, false><<<N / 64, 256, 0, stream>>>(h16, invd, nbr, W0f, b0, h1);
    layer_kernel<128, 128, true, false><<<N / 64, 256, 0, stream>>>(h1, invd, nbr, W1f, b1, h2);

    // Move what layer 2 needs out of d_out (h1 is dead now).
    hipMemcpyAsync(invd2, invd, 4194304, hipMemcpyDeviceToDevice, stream);
    hipMemcpyAsync(W2f2, W2f, 32768, hipMemcpyDeviceToDevice, stream);

    layer_kernel<128, 16, false, true><<<N / 64, 256, 0, stream>>>(h2, invd2, nbr, W2f2, b2, d_out);
}